// Round 8
// baseline (489.692 us; speedup 1.0000x reference)
//
#include <hip/hip_runtime.h>

typedef unsigned short u16;
typedef float f32x4 __attribute__((ext_vector_type(4)));
typedef u16   u16x4 __attribute__((ext_vector_type(4)));
typedef u16   u16x8 __attribute__((ext_vector_type(8)));
typedef __bf16 bf16x8 __attribute__((ext_vector_type(8)));

static __device__ __forceinline__ u16 f2bf(float x) {
    unsigned int u = __builtin_bit_cast(unsigned int, x);
    u = (u + 0x7FFFu + ((u >> 16) & 1u)) >> 16;
    return (u16)u;
}
static __device__ __forceinline__ float bf2f(u16 x) {
    unsigned int u = ((unsigned int)x) << 16;
    return __builtin_bit_cast(float, u);
}
static __device__ __forceinline__ bf16x8 as_bf(u16x8 v) { return __builtin_bit_cast(bf16x8, v); }

// async global->LDS, 16B per lane; LDS dest = wave-uniform base + lane*16
static __device__ __forceinline__ void gload16(const u16* g, u16* lds) {
    __builtin_amdgcn_global_load_lds(
        (const __attribute__((address_space(1))) void*)g,
        (__attribute__((address_space(3))) void*)lds,
        16, 0, 0);
}

#define KSCALE 0.045084220027780106f   /* log2(e)/32 */

// Stage a [rows x 64] u16 tile into LDS; read-side XOR swizzle baked into the
// per-lane GLOBAL address (LDS image = linear dest, swizzled source).
#define STAGE_G2L(dst, src, stride, ROUNDS) do {                               \
    _Pragma("unroll") for (int i_ = 0; i_ < (ROUNDS); ++i_) {                  \
        int c_ = (i_ * 4 + w) * 64 + l;                                        \
        int row_ = c_ >> 3, c8_ = c_ & 7;                                      \
        gload16((src) + (size_t)row_ * (stride) + ((c8_ ^ (row_ & 7)) << 3),   \
                &(dst)[(i_ * 4 + w) * 512]);                                   \
    } } while (0)

// ---------------------------------------------------------------------------
// Kernel 1: W [1024 d_in][1024 d_out] fp32  ->  Wt [mat][1024 d_out][1024 d_in] bf16
// ---------------------------------------------------------------------------
__global__ __launch_bounds__(256) void wt_kernel(const float* __restrict__ Wq,
                                                 const float* __restrict__ Wk,
                                                 const float* __restrict__ Wv,
                                                 u16* __restrict__ Wt) {
    __shared__ float tile[64][65];
    const int mat = blockIdx.z;
    const float* W = (mat == 0) ? Wq : ((mat == 1) ? Wk : Wv);
    const int bx = blockIdx.x, by = blockIdx.y;
    const int tid = threadIdx.x;
#pragma unroll
    for (int i = 0; i < 16; ++i) {
        int idx = i * 256 + tid;
        int r = idx >> 6, c = idx & 63;
        tile[r][c] = W[(by * 64 + r) * 1024 + bx * 64 + c];
    }
    __syncthreads();
#pragma unroll
    for (int i = 0; i < 16; ++i) {
        int idx = i * 256 + tid;
        int r = idx >> 6, c = idx & 63;
        Wt[mat * 1048576 + (bx * 64 + r) * 1024 + by * 64 + c] = f2bf(tile[c][r]);
    }
}

// ---------------------------------------------------------------------------
// Kernel 2: per-batch QKV GEMM. C[4096][3072] = X_b * Wt^T. (unchanged)
// ---------------------------------------------------------------------------
__global__ __launch_bounds__(256, 3) void qkv_gemm(const float* __restrict__ X,
                                                   const u16* __restrict__ Wt,
                                                   u16* __restrict__ Qo,
                                                   u16* __restrict__ Ko,
                                                   u16* __restrict__ Vt) {
    __shared__ u16 As[128 * 64];
    __shared__ u16 Bs[128 * 64];
    const int bid = blockIdx.x;
    const int swz = (bid & 7) * 96 + (bid >> 3);   // 768 blocks, XCD-bijective
    const int bm = swz / 24, bn = swz % 24;
    const int tid = threadIdx.x;
    const int w = tid >> 6, l = tid & 63, lg = l >> 4, lr = l & 15;
    const int wr = w >> 1, wc = w & 1;

    const f32x4 z4 = {0.f, 0.f, 0.f, 0.f};
    f32x4 acc[4][4];
#pragma unroll
    for (int m = 0; m < 4; ++m)
#pragma unroll
        for (int n = 0; n < 4; ++n) acc[m][n] = z4;

    for (int kb = 0; kb < 16; ++kb) {
        __syncthreads();
        STAGE_G2L(Bs, Wt + (size_t)(bn * 128) * 1024 + kb * 64, 1024, 4);
#pragma unroll
        for (int i = 0; i < 4; ++i) {
            int cid = i * 256 + tid;
            int row = cid >> 3, c8 = cid & 7;
            const float* src = X + (bm * 128 + row) * 1024 + kb * 64 + c8 * 8;
            f32x4 v0 = *(const f32x4*)(src);
            f32x4 v1 = *(const f32x4*)(src + 4);
            u16x8 t;
            t[0] = f2bf(v0[0]); t[1] = f2bf(v0[1]); t[2] = f2bf(v0[2]); t[3] = f2bf(v0[3]);
            t[4] = f2bf(v1[0]); t[5] = f2bf(v1[1]); t[6] = f2bf(v1[2]); t[7] = f2bf(v1[3]);
            *(u16x8*)(&As[row * 64 + ((c8 ^ (row & 7)) << 3)]) = t;
        }
        __syncthreads();
#pragma unroll
        for (int kk = 0; kk < 2; ++kk) {
            bf16x8 af[4], bfr[4];
#pragma unroll
            for (int m = 0; m < 4; ++m) {
                int row = wr * 64 + m * 16 + lr;
                af[m] = as_bf(*(const u16x8*)(&As[row * 64 + (((kk * 4 + lg) ^ (lr & 7)) << 3)]));
            }
#pragma unroll
            for (int n = 0; n < 4; ++n) {
                int row = wc * 64 + n * 16 + lr;
                bfr[n] = as_bf(*(const u16x8*)(&Bs[row * 64 + (((kk * 4 + lg) ^ (lr & 7)) << 3)]));
            }
#pragma unroll
            for (int m = 0; m < 4; ++m)
#pragma unroll
                for (int n = 0; n < 4; ++n)
                    acc[m][n] = __builtin_amdgcn_mfma_f32_16x16x32_bf16(af[m], bfr[n], acc[m][n], 0, 0, 0);
        }
    }
    const int row0 = bm * 128 + wr * 64;
    const int col0 = bn * 128 + wc * 64;
#pragma unroll
    for (int m = 0; m < 4; ++m) {
#pragma unroll
        for (int n = 0; n < 4; ++n) {
            int col = col0 + n * 16 + lr;
            int mat = col >> 10;
            int cg = col & 1023;
            int row = row0 + m * 16 + lg * 4;
            if (mat == 2) {
                u16x4 v;
                v[0] = f2bf(acc[m][n][0]); v[1] = f2bf(acc[m][n][1]);
                v[2] = f2bf(acc[m][n][2]); v[3] = f2bf(acc[m][n][3]);
                *(u16x4*)(Vt + cg * 4096 + row) = v;
            } else {
                u16* P = mat ? Ko : Qo;
#pragma unroll
                for (int r = 0; r < 4; ++r) P[(row + r) * 1024 + cg] = f2bf(acc[m][n][r]);
            }
        }
    }
}

// ---------------------------------------------------------------------------
// Kernel 3: per-batch QK^T -> P = exp2(QK^T * c) bf16. Counted-vmcnt deep
// pipeline: 256x256 tile, BK=32, 4 LDS K-tile buffers (128 KB), prefetch
// depth 3, one barrier + vmcnt(8) per K-tile (never drains to 0 mid-loop).
// LDS is frag-linear: frag f = 1KB, lane l reads bytes [l*16, +16) -> the
// canonical conflict-free ds_read_b128 pattern. 8 waves (2M x 4N).
// ---------------------------------------------------------------------------
__global__ __launch_bounds__(512, 2) void qk_8ph(const u16* __restrict__ Qb,
                                                 const u16* __restrict__ Kb,
                                                 u16* __restrict__ P) {
    __shared__ u16 lds[4][32 * 512];               // 4 bufs x (16 A + 16 B frags)
    const int bid = blockIdx.x;
    const int swz = (bid & 7) * 32 + (bid >> 3);   // 256 blocks, XCD-bijective
    const int bm = swz >> 4, bn = swz & 15;
    const int tid = threadIdx.x;
    const int w = tid >> 6, l = tid & 63, lg = l >> 4, lr = l & 15;
    const int wr = w >> 2, wc = w & 3;             // 2M x 4N wave grid

    // Wave w stages frags f = 4w..4w+3 of each K-tile.
    // Frag f<16: A = Q rows bm*256+f*16 ; f>=16: B = K rows bn*256+(f-16)*16.
    // Lane l sources row (l&15), k-chunk (l>>4)*8 of the frag -> frag-linear LDS.
    const u16* gsrc[4];
#pragma unroll
    for (int i = 0; i < 4; ++i) {
        int f = w * 4 + i;
        const u16* base = (f < 16) ? (Qb + (size_t)(bm * 256 + f * 16) * 1024)
                                   : (Kb + (size_t)(bn * 256 + (f - 16) * 16) * 1024);
        gsrc[i] = base + (size_t)lr * 1024 + lg * 8;
    }

#define STAGE8(kt) do {                                                        \
    u16* dst_ = &lds[(kt) & 3][w * 4 * 512];                                   \
    _Pragma("unroll") for (int i_ = 0; i_ < 4; ++i_)                           \
        gload16(gsrc[i_] + (kt) * 32, dst_ + i_ * 512);                        \
    } while (0)

    const f32x4 z4 = {0.f, 0.f, 0.f, 0.f};
    f32x4 acc[8][4];
#pragma unroll
    for (int mi = 0; mi < 8; ++mi)
#pragma unroll
        for (int ni = 0; ni < 4; ++ni) acc[mi][ni] = z4;

    // prologue: prefetch K-tiles 0,1,2 (12 loads/wave in flight)
    STAGE8(0); STAGE8(1); STAGE8(2);

#pragma unroll
    for (int kt = 0; kt < 32; ++kt) {
        // entry wait: tile kt landed; kt+1, kt+2 stay in flight (counted, not 0)
        if (kt <= 29)      asm volatile("s_waitcnt vmcnt(8)" ::: "memory");
        else if (kt == 30) asm volatile("s_waitcnt vmcnt(4)" ::: "memory");
        else               asm volatile("s_waitcnt vmcnt(0)" ::: "memory");
        __builtin_amdgcn_sched_barrier(0);
        __builtin_amdgcn_s_barrier();
        __builtin_amdgcn_sched_barrier(0);
        // stage kt+3 into buf[(kt-1)&3] (all waves' reads of it precede this barrier)
        if (kt < 29) STAGE8(kt + 3);
        const u16* A = &lds[kt & 3][0];
        const u16* B = &lds[kt & 3][16 * 512];
        bf16x8 bfr[4];
#pragma unroll
        for (int ni = 0; ni < 4; ++ni)
            bfr[ni] = as_bf(*(const u16x8*)(B + (wc * 4 + ni) * 512 + l * 8));
        bf16x8 af[8];
#pragma unroll
        for (int mi = 0; mi < 8; ++mi)
            af[mi] = as_bf(*(const u16x8*)(A + (wr * 8 + mi) * 512 + l * 8));
        __builtin_amdgcn_s_setprio(1);
#pragma unroll
        for (int mi = 0; mi < 8; ++mi)
#pragma unroll
            for (int ni = 0; ni < 4; ++ni)
                acc[mi][ni] = __builtin_amdgcn_mfma_f32_16x16x32_bf16(af[mi], bfr[ni], acc[mi][ni], 0, 0, 0);
        __builtin_amdgcn_s_setprio(0);
    }
#undef STAGE8

    // epilogue: P = exp2(s * c) bf16
    const int row0 = bm * 256 + wr * 128;
    const int col0 = bn * 256 + wc * 64;
#pragma unroll
    for (int mi = 0; mi < 8; ++mi) {
#pragma unroll
        for (int r = 0; r < 4; ++r) {
            const size_t rowg = (size_t)(row0 + mi * 16 + lg * 4 + r);
#pragma unroll
            for (int ni = 0; ni < 4; ++ni)
                P[rowg * 4096 + col0 + ni * 16 + lr] = f2bf(exp2f(acc[mi][ni][r] * KSCALE));
        }
    }
}

// ---------------------------------------------------------------------------
// Kernel 4: row sums of the P pair -> rlb[gw] = 1/sum (f32). (unchanged)
// ---------------------------------------------------------------------------
__global__ __launch_bounds__(256) void rowsum_pair(const u16* __restrict__ P0,
                                                   const u16* __restrict__ P1,
                                                   float* __restrict__ rlb) {
    const int gw = blockIdx.x * 4 + (threadIdx.x >> 6);
    const int l = threadIdx.x & 63;
    const u16* P = (gw < 4096) ? P0 : P1;
    const u16* pr = P + (size_t)(gw & 4095) * 4096 + l * 8;
    float s = 0.f;
#pragma unroll
    for (int j = 0; j < 8; ++j) {
        u16x8 v = *(const u16x8*)(pr + j * 512);
#pragma unroll
        for (int e = 0; e < 8; ++e) s += bf2f(v[e]);
    }
    s += __shfl_xor(s, 1, 64);
    s += __shfl_xor(s, 2, 64);
    s += __shfl_xor(s, 4, 64);
    s += __shfl_xor(s, 8, 64);
    s += __shfl_xor(s, 16, 64);
    s += __shfl_xor(s, 32, 64);
    if (l == 0) rlb[gw] = 1.0f / s;
}

// ---------------------------------------------------------------------------
// Kernel 5: pair-fused PV GEMM. (unchanged)
// ---------------------------------------------------------------------------
__global__ __launch_bounds__(256, 4) void pv_pair(const u16* __restrict__ P0,
                                                  const u16* __restrict__ P1,
                                                  const u16* __restrict__ V0,
                                                  const u16* __restrict__ V1,
                                                  const float* __restrict__ rlb,
                                                  float* __restrict__ Out0,
                                                  float* __restrict__ Out1) {
    __shared__ u16 As[128 * 64];
    __shared__ u16 Bs[128 * 64];
    __shared__ float rl_s[128];
    const int bid = blockIdx.x;
    const int swz = (bid & 7) * 64 + (bid >> 3);   // 512 blocks, XCD-bijective
    const int bb = swz >> 8, rem = swz & 255;
    const int bm = rem >> 3, bn = rem & 7;
    const int q0 = bm * 128, e0 = bn * 128;
    const u16* P  = bb ? P1 : P0;
    const u16* Vt = bb ? V1 : V0;
    float* Out    = bb ? Out1 : Out0;
    const int tid = threadIdx.x;
    const int w = tid >> 6, l = tid & 63, lg = l >> 4, lr = l & 15;
    const int wr = w >> 1, wc = w & 1;

    if (tid < 128) rl_s[tid] = rlb[bb * 4096 + q0 + tid];

    const f32x4 z4 = {0.f, 0.f, 0.f, 0.f};
    f32x4 acc[4][4];
#pragma unroll
    for (int m = 0; m < 4; ++m)
#pragma unroll
        for (int n = 0; n < 4; ++n) acc[m][n] = z4;

    for (int kb = 0; kb < 64; ++kb) {
        __syncthreads();
        STAGE_G2L(As, P + (size_t)q0 * 4096 + kb * 64, 4096, 4);
        STAGE_G2L(Bs, Vt + (size_t)e0 * 4096 + kb * 64, 4096, 4);
        __syncthreads();
#pragma unroll
        for (int kk = 0; kk < 2; ++kk) {
            bf16x8 af[4], bfr[4];
#pragma unroll
            for (int m = 0; m < 4; ++m) {
                int row = wr * 64 + m * 16 + lr;
                af[m] = as_bf(*(const u16x8*)(&As[row * 64 + (((kk * 4 + lg) ^ (lr & 7)) << 3)]));
            }
#pragma unroll
            for (int n = 0; n < 4; ++n) {
                int row = wc * 64 + n * 16 + lr;
                bfr[n] = as_bf(*(const u16x8*)(&Bs[row * 64 + (((kk * 4 + lg) ^ (lr & 7)) << 3)]));
            }
#pragma unroll
            for (int m = 0; m < 4; ++m)
#pragma unroll
                for (int n = 0; n < 4; ++n)
                    acc[m][n] = __builtin_amdgcn_mfma_f32_16x16x32_bf16(af[m], bfr[n], acc[m][n], 0, 0, 0);
        }
    }
#pragma unroll
    for (int m = 0; m < 4; ++m) {
#pragma unroll
        for (int r = 0; r < 4; ++r) {
            int rloc = wr * 64 + m * 16 + lg * 4 + r;
            float rl = rl_s[rloc];
#pragma unroll
            for (int n = 0; n < 4; ++n)
                Out[(size_t)(q0 + rloc) * 1024 + e0 + wc * 64 + n * 16 + lr] = acc[m][n][r] * rl;
        }
    }
}

// ---------------------------------------------------------------------------
extern "C" void kernel_launch(void* const* d_in, const int* in_sizes, int n_in,
                              void* d_out, int out_size, void* d_ws, size_t ws_size,
                              hipStream_t stream) {
    const float* x  = (const float*)d_in[0];
    const float* Wq = (const float*)d_in[1];
    const float* Wk = (const float*)d_in[2];
    const float* Wv = (const float*)d_in[3];
    float* out = (float*)d_out;

    char* ws = (char*)d_ws;
    u16* Wt = (u16*)(ws);                        //  6,291,456 B
    u16* Qb = (u16*)(ws + 6291456);              //  8,388,608 B (first 32 KB double as rlb)
    u16* Kb = (u16*)(ws + 14680064);             //  8,388,608 B
    u16* V0 = (u16*)(ws + 23068672);             //  8,388,608 B
    u16* V1 = (u16*)(ws + 31457280);             //  8,388,608 B
    u16* P0 = (u16*)(ws + 39845888);             // 33,554,432 B
    u16* P1 = (u16*)(ws + 73400320);             // 33,554,432 B  (total 106,954,752)
    float* rlb = (float*)Qb;                     // rl lives in Qb (dead between qk(b1) and next qkv)

    wt_kernel<<<dim3(16, 16, 3), 256, 0, stream>>>(Wq, Wk, Wv, Wt);
    for (int p = 0; p < 2; ++p) {
        const float* x0 = x + (size_t)(2 * p) * 4194304;
        const float* x1 = x + (size_t)(2 * p + 1) * 4194304;
        float* o0 = out + (size_t)(2 * p) * 4194304;
        float* o1 = out + (size_t)(2 * p + 1) * 4194304;
        qkv_gemm<<<dim3(768), 256, 0, stream>>>(x0, Wt, Qb, Kb, V0);
        qk_8ph<<<dim3(256), 512, 0, stream>>>(Qb, Kb, P0);
        qkv_gemm<<<dim3(768), 256, 0, stream>>>(x1, Wt, Qb, Kb, V1);
        qk_8ph<<<dim3(256), 512, 0, stream>>>(Qb, Kb, P1);
        rowsum_pair<<<dim3(2048), 256, 0, stream>>>(P0, P1, rlb);
        pv_pair<<<dim3(512), 256, 0, stream>>>(P0, P1, V0, V1, rlb, o0, o1);
    }
}

// Round 9
// 475.963 us; speedup vs baseline: 1.0288x; 1.0288x over previous
//
#include <hip/hip_runtime.h>

typedef unsigned short u16;
typedef float f32x4 __attribute__((ext_vector_type(4)));
typedef u16   u16x4 __attribute__((ext_vector_type(4)));
typedef u16   u16x8 __attribute__((ext_vector_type(8)));
typedef __bf16 bf16x8 __attribute__((ext_vector_type(8)));

static __device__ __forceinline__ u16 f2bf(float x) {
    unsigned int u = __builtin_bit_cast(unsigned int, x);
    u = (u + 0x7FFFu + ((u >> 16) & 1u)) >> 16;
    return (u16)u;
}
static __device__ __forceinline__ bf16x8 as_bf(u16x8 v) { return __builtin_bit_cast(bf16x8, v); }

// async global->LDS, 16B per lane; LDS dest = wave-uniform base + lane*16
static __device__ __forceinline__ void gload16(const u16* g, u16* lds) {
    __builtin_amdgcn_global_load_lds(
        (const __attribute__((address_space(1))) void*)g,
        (__attribute__((address_space(3))) void*)lds,
        16, 0, 0);
}

#define KSCALE 0.045084220027780106f   /* log2(e)/32 */

// Stage a [rows x 64] u16 tile into LDS; read-side XOR swizzle baked into the
// per-lane GLOBAL address (LDS image = linear dest, swizzled source).
#define STAGE_G2L(dst, src, stride, ROUNDS) do {                               \
    _Pragma("unroll") for (int i_ = 0; i_ < (ROUNDS); ++i_) {                  \
        int c_ = (i_ * 4 + w) * 64 + l;                                        \
        int row_ = c_ >> 3, c8_ = c_ & 7;                                      \
        gload16((src) + (size_t)row_ * (stride) + ((c8_ ^ (row_ & 7)) << 3),   \
                &(dst)[(i_ * 4 + w) * 512]);                                   \
    } } while (0)

// ---------------------------------------------------------------------------
// Kernel 1: W [1024 d_in][1024 d_out] fp32  ->  Wt [mat][1024 d_out][1024 d_in] bf16
// ---------------------------------------------------------------------------
__global__ __launch_bounds__(256) void wt_kernel(const float* __restrict__ Wq,
                                                 const float* __restrict__ Wk,
                                                 const float* __restrict__ Wv,
                                                 u16* __restrict__ Wt) {
    __shared__ float tile[64][65];
    const int mat = blockIdx.z;
    const float* W = (mat == 0) ? Wq : ((mat == 1) ? Wk : Wv);
    const int bx = blockIdx.x, by = blockIdx.y;
    const int tid = threadIdx.x;
#pragma unroll
    for (int i = 0; i < 16; ++i) {
        int idx = i * 256 + tid;
        int r = idx >> 6, c = idx & 63;
        tile[r][c] = W[(by * 64 + r) * 1024 + bx * 64 + c];
    }
    __syncthreads();
#pragma unroll
    for (int i = 0; i < 16; ++i) {
        int idx = i * 256 + tid;
        int r = idx >> 6, c = idx & 63;
        Wt[mat * 1048576 + (bx * 64 + r) * 1024 + by * 64 + c] = f2bf(tile[c][r]);
    }
}

// ---------------------------------------------------------------------------
// Kernel 2: per-batch QKV GEMM. C[4096][3072] = X_b * Wt^T.
// Q,K row-major bf16 [4096][1024]; V transposed: Vt[1024 e][4096 k] bf16.
// ---------------------------------------------------------------------------
__global__ __launch_bounds__(256, 3) void qkv_gemm(const float* __restrict__ X,
                                                   const u16* __restrict__ Wt,
                                                   u16* __restrict__ Qo,
                                                   u16* __restrict__ Ko,
                                                   u16* __restrict__ Vt) {
    __shared__ u16 As[128 * 64];
    __shared__ u16 Bs[128 * 64];
    const int bid = blockIdx.x;
    const int swz = (bid & 7) * 96 + (bid >> 3);   // 768 blocks, XCD-bijective
    const int bm = swz / 24, bn = swz % 24;
    const int tid = threadIdx.x;
    const int w = tid >> 6, l = tid & 63, lg = l >> 4, lr = l & 15;
    const int wr = w >> 1, wc = w & 1;

    const f32x4 z4 = {0.f, 0.f, 0.f, 0.f};
    f32x4 acc[4][4];
#pragma unroll
    for (int m = 0; m < 4; ++m)
#pragma unroll
        for (int n = 0; n < 4; ++n) acc[m][n] = z4;

    for (int kb = 0; kb < 16; ++kb) {
        __syncthreads();
        STAGE_G2L(Bs, Wt + (size_t)(bn * 128) * 1024 + kb * 64, 1024, 4);
#pragma unroll
        for (int i = 0; i < 4; ++i) {
            int cid = i * 256 + tid;
            int row = cid >> 3, c8 = cid & 7;
            const float* src = X + (bm * 128 + row) * 1024 + kb * 64 + c8 * 8;
            f32x4 v0 = *(const f32x4*)(src);
            f32x4 v1 = *(const f32x4*)(src + 4);
            u16x8 t;
            t[0] = f2bf(v0[0]); t[1] = f2bf(v0[1]); t[2] = f2bf(v0[2]); t[3] = f2bf(v0[3]);
            t[4] = f2bf(v1[0]); t[5] = f2bf(v1[1]); t[6] = f2bf(v1[2]); t[7] = f2bf(v1[3]);
            *(u16x8*)(&As[row * 64 + ((c8 ^ (row & 7)) << 3)]) = t;
        }
        __syncthreads();
#pragma unroll
        for (int kk = 0; kk < 2; ++kk) {
            bf16x8 af[4], bfr[4];
#pragma unroll
            for (int m = 0; m < 4; ++m) {
                int row = wr * 64 + m * 16 + lr;
                af[m] = as_bf(*(const u16x8*)(&As[row * 64 + (((kk * 4 + lg) ^ (lr & 7)) << 3)]));
            }
#pragma unroll
            for (int n = 0; n < 4; ++n) {
                int row = wc * 64 + n * 16 + lr;
                bfr[n] = as_bf(*(const u16x8*)(&Bs[row * 64 + (((kk * 4 + lg) ^ (lr & 7)) << 3)]));
            }
#pragma unroll
            for (int m = 0; m < 4; ++m)
#pragma unroll
                for (int n = 0; n < 4; ++n)
                    acc[m][n] = __builtin_amdgcn_mfma_f32_16x16x32_bf16(af[m], bfr[n], acc[m][n], 0, 0, 0);
        }
    }
    const int row0 = bm * 128 + wr * 64;
    const int col0 = bn * 128 + wc * 64;
#pragma unroll
    for (int m = 0; m < 4; ++m) {
#pragma unroll
        for (int n = 0; n < 4; ++n) {
            int col = col0 + n * 16 + lr;
            int mat = col >> 10;
            int cg = col & 1023;
            int row = row0 + m * 16 + lg * 4;
            if (mat == 2) {
                u16x4 v;
                v[0] = f2bf(acc[m][n][0]); v[1] = f2bf(acc[m][n][1]);
                v[2] = f2bf(acc[m][n][2]); v[3] = f2bf(acc[m][n][3]);
                *(u16x4*)(Vt + cg * 4096 + row) = v;
            } else {
                u16* P = mat ? Ko : Qo;
#pragma unroll
                for (int r = 0; r < 4; ++r) P[(row + r) * 1024 + cg] = f2bf(acc[m][n][r]);
            }
        }
    }
}

// ---------------------------------------------------------------------------
// Kernel 3: per-batch QK^T GEMM -> P[4096 q][4096 k] bf16 = exp2(QK^T * c)
// (unnormalized numerator; logits tiny). Proven 128x128 / BK=64 structure.
// ---------------------------------------------------------------------------
__global__ __launch_bounds__(256, 4) void qk_gemm(const u16* __restrict__ Qb,
                                                  const u16* __restrict__ Kb,
                                                  u16* __restrict__ P) {
    __shared__ u16 As[128 * 64];
    __shared__ u16 Bs[128 * 64];
    const int bid = blockIdx.x;
    const int swz = (bid & 7) * 128 + (bid >> 3);  // 1024 blocks
    const int bm = swz >> 5, bn = swz & 31;
    const int tid = threadIdx.x;
    const int w = tid >> 6, l = tid & 63, lg = l >> 4, lr = l & 15;
    const int wr = w >> 1, wc = w & 1;

    const f32x4 z4 = {0.f, 0.f, 0.f, 0.f};
    f32x4 acc[4][4];
#pragma unroll
    for (int m = 0; m < 4; ++m)
#pragma unroll
        for (int n = 0; n < 4; ++n) acc[m][n] = z4;

    for (int kb = 0; kb < 16; ++kb) {
        __syncthreads();
        STAGE_G2L(As, Qb + (size_t)(bm * 128) * 1024 + kb * 64, 1024, 4);
        STAGE_G2L(Bs, Kb + (size_t)(bn * 128) * 1024 + kb * 64, 1024, 4);
        __syncthreads();
#pragma unroll
        for (int kk = 0; kk < 2; ++kk) {
            bf16x8 af[4], bfr[4];
#pragma unroll
            for (int m = 0; m < 4; ++m) {
                int row = wr * 64 + m * 16 + lr;
                af[m] = as_bf(*(const u16x8*)(&As[row * 64 + (((kk * 4 + lg) ^ (lr & 7)) << 3)]));
            }
#pragma unroll
            for (int n = 0; n < 4; ++n) {
                int row = wc * 64 + n * 16 + lr;
                bfr[n] = as_bf(*(const u16x8*)(&Bs[row * 64 + (((kk * 4 + lg) ^ (lr & 7)) << 3)]));
            }
#pragma unroll
            for (int m = 0; m < 4; ++m)
#pragma unroll
                for (int n = 0; n < 4; ++n)
                    acc[m][n] = __builtin_amdgcn_mfma_f32_16x16x32_bf16(af[m], bfr[n], acc[m][n], 0, 0, 0);
        }
    }
    const int row0 = bm * 128 + wr * 64;
    const int col0 = bn * 128 + wc * 64;
#pragma unroll
    for (int m = 0; m < 4; ++m) {
#pragma unroll
        for (int r = 0; r < 4; ++r) {
            const size_t rowg = (size_t)(row0 + m * 16 + lg * 4 + r);
#pragma unroll
            for (int n = 0; n < 4; ++n)
                P[rowg * 4096 + col0 + n * 16 + lr] = f2bf(exp2f(acc[m][n][r] * KSCALE));
        }
    }
}

// ---------------------------------------------------------------------------
// Kernel 4: pair-fused PV GEMM with in-kernel softmax denominator.
// For bb in {0,1}: O_bb[4096 q][1024 e] f32 = (P_bb * V_bb) / rowsum(P_bb).
// Row sums via an extra MFMA against a ones-vector B operand: D[row][*] =
// sum_k A[row][k] accumulated over the FULL K loop == softmax denominator,
// computed from the same bf16 fragments the GEMM consumes. Each lane ends
// with its own rows' sums in acc_sum[m][r] (no cross-lane reduce needed).
// ---------------------------------------------------------------------------
__global__ __launch_bounds__(256, 4) void pv_pair(const u16* __restrict__ P0,
                                                  const u16* __restrict__ P1,
                                                  const u16* __restrict__ V0,
                                                  const u16* __restrict__ V1,
                                                  float* __restrict__ Out0,
                                                  float* __restrict__ Out1) {
    __shared__ u16 As[128 * 64];
    __shared__ u16 Bs[128 * 64];
    const int bid = blockIdx.x;
    const int swz = (bid & 7) * 64 + (bid >> 3);   // 512 blocks, XCD-bijective
    const int bb = swz >> 8, rem = swz & 255;
    const int bm = rem >> 3, bn = rem & 7;
    const int q0 = bm * 128, e0 = bn * 128;
    const u16* P  = bb ? P1 : P0;
    const u16* Vt = bb ? V1 : V0;
    float* Out    = bb ? Out1 : Out0;
    const int tid = threadIdx.x;
    const int w = tid >> 6, l = tid & 63, lg = l >> 4, lr = l & 15;
    const int wr = w >> 1, wc = w & 1;

    u16x8 ones_u;
#pragma unroll
    for (int i = 0; i < 8; ++i) ones_u[i] = 0x3F80;   // bf16 1.0
    const bf16x8 ones8 = as_bf(ones_u);

    const f32x4 z4 = {0.f, 0.f, 0.f, 0.f};
    f32x4 acc[4][4];
    f32x4 acc_sum[4];
#pragma unroll
    for (int m = 0; m < 4; ++m) {
        acc_sum[m] = z4;
#pragma unroll
        for (int n = 0; n < 4; ++n) acc[m][n] = z4;
    }

    for (int kb = 0; kb < 64; ++kb) {
        __syncthreads();
        STAGE_G2L(As, P + (size_t)q0 * 4096 + kb * 64, 4096, 4);
        STAGE_G2L(Bs, Vt + (size_t)e0 * 4096 + kb * 64, 4096, 4);
        __syncthreads();
#pragma unroll
        for (int kk = 0; kk < 2; ++kk) {
            bf16x8 af[4], bfr[4];
#pragma unroll
            for (int m = 0; m < 4; ++m) {
                int row = wr * 64 + m * 16 + lr;
                af[m] = as_bf(*(const u16x8*)(&As[row * 64 + (((kk * 4 + lg) ^ (lr & 7)) << 3)]));
            }
#pragma unroll
            for (int n = 0; n < 4; ++n) {
                int row = wc * 64 + n * 16 + lr;
                bfr[n] = as_bf(*(const u16x8*)(&Bs[row * 64 + (((kk * 4 + lg) ^ (lr & 7)) << 3)]));
            }
#pragma unroll
            for (int m = 0; m < 4; ++m) {
#pragma unroll
                for (int n = 0; n < 4; ++n)
                    acc[m][n] = __builtin_amdgcn_mfma_f32_16x16x32_bf16(af[m], bfr[n], acc[m][n], 0, 0, 0);
                acc_sum[m] = __builtin_amdgcn_mfma_f32_16x16x32_bf16(af[m], ones8, acc_sum[m], 0, 0, 0);
            }
        }
    }
    // epilogue: divide by rowsum (lane-local), store f32
#pragma unroll
    for (int m = 0; m < 4; ++m) {
#pragma unroll
        for (int r = 0; r < 4; ++r) {
            int rloc = wr * 64 + m * 16 + lg * 4 + r;
            float rl = 1.0f / acc_sum[m][r];
#pragma unroll
            for (int n = 0; n < 4; ++n)
                Out[(size_t)(q0 + rloc) * 1024 + e0 + wc * 64 + n * 16 + lr] = acc[m][n][r] * rl;
        }
    }
}

// ---------------------------------------------------------------------------
extern "C" void kernel_launch(void* const* d_in, const int* in_sizes, int n_in,
                              void* d_out, int out_size, void* d_ws, size_t ws_size,
                              hipStream_t stream) {
    const float* x  = (const float*)d_in[0];
    const float* Wq = (const float*)d_in[1];
    const float* Wk = (const float*)d_in[2];
    const float* Wv = (const float*)d_in[3];
    float* out = (float*)d_out;

    char* ws = (char*)d_ws;
    u16* Wt = (u16*)(ws);                        //  6,291,456 B
    u16* Qb = (u16*)(ws + 6291456);              //  8,388,608 B
    u16* Kb = (u16*)(ws + 14680064);             //  8,388,608 B
    u16* V0 = (u16*)(ws + 23068672);             //  8,388,608 B
    u16* V1 = (u16*)(ws + 31457280);             //  8,388,608 B
    u16* P0 = (u16*)(ws + 39845888);             // 33,554,432 B
    u16* P1 = (u16*)(ws + 73400320);             // 33,554,432 B  (total 106,954,752)

    wt_kernel<<<dim3(16, 16, 3), 256, 0, stream>>>(Wq, Wk, Wv, Wt);
    for (int p = 0; p < 2; ++p) {
        const float* x0 = x + (size_t)(2 * p) * 4194304;
        const float* x1 = x + (size_t)(2 * p + 1) * 4194304;
        float* o0 = out + (size_t)(2 * p) * 4194304;
        float* o1 = out + (size_t)(2 * p + 1) * 4194304;
        qkv_gemm<<<dim3(768), 256, 0, stream>>>(x0, Wt, Qb, Kb, V0);
        qk_gemm<<<dim3(1024), 256, 0, stream>>>(Qb, Kb, P0);
        qkv_gemm<<<dim3(768), 256, 0, stream>>>(x1, Wt, Qb, Kb, V1);
        qk_gemm<<<dim3(1024), 256, 0, stream>>>(Qb, Kb, P1);
        pv_pair<<<dim3(512), 256, 0, stream>>>(P0, P1, V0, V1, o0, o1);
    }
}

// Round 10
// 452.572 us; speedup vs baseline: 1.0820x; 1.0517x over previous
//
#include <hip/hip_runtime.h>

typedef unsigned short u16;
typedef float f32x4 __attribute__((ext_vector_type(4)));
typedef u16   u16x4 __attribute__((ext_vector_type(4)));
typedef u16   u16x8 __attribute__((ext_vector_type(8)));
typedef __bf16 bf16x8 __attribute__((ext_vector_type(8)));

static __device__ __forceinline__ u16 f2bf(float x) {
    unsigned int u = __builtin_bit_cast(unsigned int, x);
    u = (u + 0x7FFFu + ((u >> 16) & 1u)) >> 16;
    return (u16)u;
}
static __device__ __forceinline__ float bf2f(u16 x) {
    unsigned int u = ((unsigned int)x) << 16;
    return __builtin_bit_cast(float, u);
}
static __device__ __forceinline__ bf16x8 as_bf(u16x8 v) { return __builtin_bit_cast(bf16x8, v); }

// async global->LDS, 16B per lane; LDS dest = wave-uniform base + lane*16
static __device__ __forceinline__ void gload16(const u16* g, u16* lds) {
    __builtin_amdgcn_global_load_lds(
        (const __attribute__((address_space(1))) void*)g,
        (__attribute__((address_space(3))) void*)lds,
        16, 0, 0);
}

#define KSCALE 0.045084220027780106f   /* log2(e)/32 */

// Stage a [rows x 64] u16 tile into LDS; read-side XOR swizzle baked into the
// per-lane GLOBAL address (LDS image = linear dest, swizzled source).
#define STAGE_G2L(dst, src, stride, ROUNDS) do {                               \
    _Pragma("unroll") for (int i_ = 0; i_ < (ROUNDS); ++i_) {                  \
        int c_ = (i_ * 4 + w) * 64 + l;                                        \
        int row_ = c_ >> 3, c8_ = c_ & 7;                                      \
        gload16((src) + (size_t)row_ * (stride) + ((c8_ ^ (row_ & 7)) << 3),   \
                &(dst)[(i_ * 4 + w) * 512]);                                   \
    } } while (0)

// ---------------------------------------------------------------------------
// Kernel 1: W [1024 d_in][1024 d_out] fp32  ->  Wt [mat][1024 d_out][1024 d_in] bf16
// ---------------------------------------------------------------------------
__global__ __launch_bounds__(256) void wt_kernel(const float* __restrict__ Wq,
                                                 const float* __restrict__ Wk,
                                                 const float* __restrict__ Wv,
                                                 u16* __restrict__ Wt) {
    __shared__ float tile[64][65];
    const int mat = blockIdx.z;
    const float* W = (mat == 0) ? Wq : ((mat == 1) ? Wk : Wv);
    const int bx = blockIdx.x, by = blockIdx.y;
    const int tid = threadIdx.x;
#pragma unroll
    for (int i = 0; i < 16; ++i) {
        int idx = i * 256 + tid;
        int r = idx >> 6, c = idx & 63;
        tile[r][c] = W[(by * 64 + r) * 1024 + bx * 64 + c];
    }
    __syncthreads();
#pragma unroll
    for (int i = 0; i < 16; ++i) {
        int idx = i * 256 + tid;
        int r = idx >> 6, c = idx & 63;
        Wt[mat * 1048576 + (bx * 64 + r) * 1024 + by * 64 + c] = f2bf(tile[c][r]);
    }
}

// ---------------------------------------------------------------------------
// Kernel 2: per-batch QKV GEMM. C[4096][3072] = X_b * Wt^T.
// Q,K row-major bf16 [4096][1024]; V transposed: Vt[1024 e][4096 k] bf16.
// ---------------------------------------------------------------------------
__global__ __launch_bounds__(256, 3) void qkv_gemm(const float* __restrict__ X,
                                                   const u16* __restrict__ Wt,
                                                   u16* __restrict__ Qo,
                                                   u16* __restrict__ Ko,
                                                   u16* __restrict__ Vt) {
    __shared__ u16 As[128 * 64];
    __shared__ u16 Bs[128 * 64];
    const int bid = blockIdx.x;
    const int swz = (bid & 7) * 96 + (bid >> 3);   // 768 blocks, XCD-bijective
    const int bm = swz / 24, bn = swz % 24;
    const int tid = threadIdx.x;
    const int w = tid >> 6, l = tid & 63, lg = l >> 4, lr = l & 15;
    const int wr = w >> 1, wc = w & 1;

    const f32x4 z4 = {0.f, 0.f, 0.f, 0.f};
    f32x4 acc[4][4];
#pragma unroll
    for (int m = 0; m < 4; ++m)
#pragma unroll
        for (int n = 0; n < 4; ++n) acc[m][n] = z4;

    for (int kb = 0; kb < 16; ++kb) {
        __syncthreads();
        STAGE_G2L(Bs, Wt + (size_t)(bn * 128) * 1024 + kb * 64, 1024, 4);
#pragma unroll
        for (int i = 0; i < 4; ++i) {
            int cid = i * 256 + tid;
            int row = cid >> 3, c8 = cid & 7;
            const float* src = X + (bm * 128 + row) * 1024 + kb * 64 + c8 * 8;
            f32x4 v0 = *(const f32x4*)(src);
            f32x4 v1 = *(const f32x4*)(src + 4);
            u16x8 t;
            t[0] = f2bf(v0[0]); t[1] = f2bf(v0[1]); t[2] = f2bf(v0[2]); t[3] = f2bf(v0[3]);
            t[4] = f2bf(v1[0]); t[5] = f2bf(v1[1]); t[6] = f2bf(v1[2]); t[7] = f2bf(v1[3]);
            *(u16x8*)(&As[row * 64 + ((c8 ^ (row & 7)) << 3)]) = t;
        }
        __syncthreads();
#pragma unroll
        for (int kk = 0; kk < 2; ++kk) {
            bf16x8 af[4], bfr[4];
#pragma unroll
            for (int m = 0; m < 4; ++m) {
                int row = wr * 64 + m * 16 + lr;
                af[m] = as_bf(*(const u16x8*)(&As[row * 64 + (((kk * 4 + lg) ^ (lr & 7)) << 3)]));
            }
#pragma unroll
            for (int n = 0; n < 4; ++n) {
                int row = wc * 64 + n * 16 + lr;
                bfr[n] = as_bf(*(const u16x8*)(&Bs[row * 64 + (((kk * 4 + lg) ^ (lr & 7)) << 3)]));
            }
#pragma unroll
            for (int m = 0; m < 4; ++m)
#pragma unroll
                for (int n = 0; n < 4; ++n)
                    acc[m][n] = __builtin_amdgcn_mfma_f32_16x16x32_bf16(af[m], bfr[n], acc[m][n], 0, 0, 0);
        }
    }
    const int row0 = bm * 128 + wr * 64;
    const int col0 = bn * 128 + wc * 64;
#pragma unroll
    for (int m = 0; m < 4; ++m) {
#pragma unroll
        for (int n = 0; n < 4; ++n) {
            int col = col0 + n * 16 + lr;
            int mat = col >> 10;
            int cg = col & 1023;
            int row = row0 + m * 16 + lg * 4;
            if (mat == 2) {
                u16x4 v;
                v[0] = f2bf(acc[m][n][0]); v[1] = f2bf(acc[m][n][1]);
                v[2] = f2bf(acc[m][n][2]); v[3] = f2bf(acc[m][n][3]);
                *(u16x4*)(Vt + cg * 4096 + row) = v;
            } else {
                u16* P = mat ? Ko : Qo;
#pragma unroll
                for (int r = 0; r < 4; ++r) P[(row + r) * 1024 + cg] = f2bf(acc[m][n][r]);
            }
        }
    }
}

// ---------------------------------------------------------------------------
// Kernel 3: per-batch QK^T GEMM -> P[4096 q][4096 k] bf16 = exp2(QK^T * c)
// (unnormalized numerator; logits tiny). 128x128 / BK=64 proven structure.
// WRITE_PL: epilogue also writes per-row partial sums pl[row*64 + bn*2 + wc]
// (sum of the SAME bf16-rounded P values over this wave-half's 64 cols);
// proven-free in rounds 5/6 (qk stayed 37.5 us with it).
// ---------------------------------------------------------------------------
template <bool WRITE_PL>
__global__ __launch_bounds__(256, 4) void qk_gemm(const u16* __restrict__ Qb,
                                                  const u16* __restrict__ Kb,
                                                  u16* __restrict__ P,
                                                  float* __restrict__ pl) {
    __shared__ u16 As[128 * 64];
    __shared__ u16 Bs[128 * 64];
    const int bid = blockIdx.x;
    const int swz = (bid & 7) * 128 + (bid >> 3);  // 1024 blocks
    const int bm = swz >> 5, bn = swz & 31;
    const int tid = threadIdx.x;
    const int w = tid >> 6, l = tid & 63, lg = l >> 4, lr = l & 15;
    const int wr = w >> 1, wc = w & 1;

    const f32x4 z4 = {0.f, 0.f, 0.f, 0.f};
    f32x4 acc[4][4];
#pragma unroll
    for (int m = 0; m < 4; ++m)
#pragma unroll
        for (int n = 0; n < 4; ++n) acc[m][n] = z4;

    for (int kb = 0; kb < 16; ++kb) {
        __syncthreads();
        STAGE_G2L(As, Qb + (size_t)(bm * 128) * 1024 + kb * 64, 1024, 4);
        STAGE_G2L(Bs, Kb + (size_t)(bn * 128) * 1024 + kb * 64, 1024, 4);
        __syncthreads();
#pragma unroll
        for (int kk = 0; kk < 2; ++kk) {
            bf16x8 af[4], bfr[4];
#pragma unroll
            for (int m = 0; m < 4; ++m) {
                int row = wr * 64 + m * 16 + lr;
                af[m] = as_bf(*(const u16x8*)(&As[row * 64 + (((kk * 4 + lg) ^ (lr & 7)) << 3)]));
            }
#pragma unroll
            for (int n = 0; n < 4; ++n) {
                int row = wc * 64 + n * 16 + lr;
                bfr[n] = as_bf(*(const u16x8*)(&Bs[row * 64 + (((kk * 4 + lg) ^ (lr & 7)) << 3)]));
            }
#pragma unroll
            for (int m = 0; m < 4; ++m)
#pragma unroll
                for (int n = 0; n < 4; ++n)
                    acc[m][n] = __builtin_amdgcn_mfma_f32_16x16x32_bf16(af[m], bfr[n], acc[m][n], 0, 0, 0);
        }
    }
    const int row0 = bm * 128 + wr * 64;
    const int col0 = bn * 128 + wc * 64;
#pragma unroll
    for (int m = 0; m < 4; ++m) {
#pragma unroll
        for (int r = 0; r < 4; ++r) {
            const size_t rowg = (size_t)(row0 + m * 16 + lg * 4 + r);
            float se = 0.f;
#pragma unroll
            for (int n = 0; n < 4; ++n) {
                u16 pb = f2bf(exp2f(acc[m][n][r] * KSCALE));
                P[rowg * 4096 + col0 + n * 16 + lr] = pb;
                if (WRITE_PL) se += bf2f(pb);
            }
            if (WRITE_PL) {
                se += __shfl_xor(se, 1, 64);
                se += __shfl_xor(se, 2, 64);
                se += __shfl_xor(se, 4, 64);
                se += __shfl_xor(se, 8, 64);
                if (lr == 0) pl[rowg * 64 + bn * 2 + wc] = se;
            }
        }
    }
}

// ---------------------------------------------------------------------------
// Kernel 4 (fallback only): row sums of the P pair -> rlb[gw] = 1/sum.
// ---------------------------------------------------------------------------
__global__ __launch_bounds__(256) void rowsum_pair(const u16* __restrict__ P0,
                                                   const u16* __restrict__ P1,
                                                   float* __restrict__ rlb) {
    const int gw = blockIdx.x * 4 + (threadIdx.x >> 6);
    const int l = threadIdx.x & 63;
    const u16* P = (gw < 4096) ? P0 : P1;
    const u16* pr = P + (size_t)(gw & 4095) * 4096 + l * 8;
    float s = 0.f;
#pragma unroll
    for (int j = 0; j < 8; ++j) {
        u16x8 v = *(const u16x8*)(pr + j * 512);
#pragma unroll
        for (int e = 0; e < 8; ++e) s += bf2f(v[e]);
    }
    s += __shfl_xor(s, 1, 64);
    s += __shfl_xor(s, 2, 64);
    s += __shfl_xor(s, 4, 64);
    s += __shfl_xor(s, 8, 64);
    s += __shfl_xor(s, 16, 64);
    s += __shfl_xor(s, 32, 64);
    if (l == 0) rlb[gw] = 1.0f / s;
}

// ---------------------------------------------------------------------------
// Kernel 5: pair-fused PV GEMM (pure bf16 GEMM, round-7 structure).
// MODE 0: pl holds 64 f32 partial sums per row -> prologue reduces to 1/sum.
// MODE 1: pl holds precomputed 1/sum per row (rlb from rowsum_pair).
// ---------------------------------------------------------------------------
template <int MODE>
__global__ __launch_bounds__(256, 4) void pv_pair(const u16* __restrict__ P0,
                                                  const u16* __restrict__ P1,
                                                  const u16* __restrict__ V0,
                                                  const u16* __restrict__ V1,
                                                  const float* __restrict__ pl,
                                                  float* __restrict__ Out0,
                                                  float* __restrict__ Out1) {
    __shared__ u16 As[128 * 64];
    __shared__ u16 Bs[128 * 64];
    __shared__ float rl_s[128];
    const int bid = blockIdx.x;
    const int swz = (bid & 7) * 64 + (bid >> 3);   // 512 blocks, XCD-bijective
    const int bb = swz >> 8, rem = swz & 255;
    const int bm = rem >> 3, bn = rem & 7;
    const int q0 = bm * 128, e0 = bn * 128;
    const u16* P  = bb ? P1 : P0;
    const u16* Vt = bb ? V1 : V0;
    float* Out    = bb ? Out1 : Out0;
    const int tid = threadIdx.x;
    const int w = tid >> 6, l = tid & 63, lg = l >> 4, lr = l & 15;
    const int wr = w >> 1, wc = w & 1;

    if (MODE == 0) {
        if (tid < 128) {
            const f32x4* pp = (const f32x4*)(pl + (size_t)(bb * 4096 + q0 + tid) * 64);
            f32x4 a = pp[0];
#pragma unroll
            for (int i = 1; i < 16; ++i) a += pp[i];
            rl_s[tid] = 1.0f / (a[0] + a[1] + a[2] + a[3]);
        }
    } else {
        if (tid < 128) rl_s[tid] = pl[bb * 4096 + q0 + tid];
    }

    const f32x4 z4 = {0.f, 0.f, 0.f, 0.f};
    f32x4 acc[4][4];
#pragma unroll
    for (int m = 0; m < 4; ++m)
#pragma unroll
        for (int n = 0; n < 4; ++n) acc[m][n] = z4;

    for (int kb = 0; kb < 64; ++kb) {
        __syncthreads();
        STAGE_G2L(As, P + (size_t)q0 * 4096 + kb * 64, 4096, 4);
        STAGE_G2L(Bs, Vt + (size_t)e0 * 4096 + kb * 64, 4096, 4);
        __syncthreads();
#pragma unroll
        for (int kk = 0; kk < 2; ++kk) {
            bf16x8 af[4], bfr[4];
#pragma unroll
            for (int m = 0; m < 4; ++m) {
                int row = wr * 64 + m * 16 + lr;
                af[m] = as_bf(*(const u16x8*)(&As[row * 64 + (((kk * 4 + lg) ^ (lr & 7)) << 3)]));
            }
#pragma unroll
            for (int n = 0; n < 4; ++n) {
                int row = wc * 64 + n * 16 + lr;
                bfr[n] = as_bf(*(const u16x8*)(&Bs[row * 64 + (((kk * 4 + lg) ^ (lr & 7)) << 3)]));
            }
#pragma unroll
            for (int m = 0; m < 4; ++m)
#pragma unroll
                for (int n = 0; n < 4; ++n)
                    acc[m][n] = __builtin_amdgcn_mfma_f32_16x16x32_bf16(af[m], bfr[n], acc[m][n], 0, 0, 0);
        }
    }
    // epilogue: multiply by 1/rowsum, store f32
#pragma unroll
    for (int m = 0; m < 4; ++m) {
#pragma unroll
        for (int r = 0; r < 4; ++r) {
            int rloc = wr * 64 + m * 16 + lg * 4 + r;
            float rl = rl_s[rloc];
#pragma unroll
            for (int n = 0; n < 4; ++n)
                Out[(size_t)(q0 + rloc) * 1024 + e0 + wc * 64 + n * 16 + lr] = acc[m][n][r] * rl;
        }
    }
}

// ---------------------------------------------------------------------------
extern "C" void kernel_launch(void* const* d_in, const int* in_sizes, int n_in,
                              void* d_out, int out_size, void* d_ws, size_t ws_size,
                              hipStream_t stream) {
    const float* x  = (const float*)d_in[0];
    const float* Wq = (const float*)d_in[1];
    const float* Wk = (const float*)d_in[2];
    const float* Wv = (const float*)d_in[3];
    float* out = (float*)d_out;

    char* ws = (char*)d_ws;
    u16* Wt = (u16*)(ws);                        //  6,291,456 B
    u16* Qb = (u16*)(ws + 6291456);              //  8,388,608 B
    u16* Kb = (u16*)(ws + 14680064);             //  8,388,608 B
    u16* V0 = (u16*)(ws + 23068672);             //  8,388,608 B
    u16* V1 = (u16*)(ws + 31457280);             //  8,388,608 B
    u16* P0 = (u16*)(ws + 39845888);             // 33,554,432 B
    u16* P1 = (u16*)(ws + 73400320);             // 33,554,432 B  (base total 106,954,752)
    float* plg = (float*)(ws + 106954752);       //  2,097,152 B  (only if ws fits)
    float* rlb = (float*)Qb;                     // fallback: rlb in dead Qb

    // ws_size is fixed across calls -> branch is deterministic.
    const bool big = (ws_size >= 106954752u + 2097152u);

    wt_kernel<<<dim3(16, 16, 3), 256, 0, stream>>>(Wq, Wk, Wv, Wt);
    for (int p = 0; p < 2; ++p) {
        const float* x0 = x + (size_t)(2 * p) * 4194304;
        const float* x1 = x + (size_t)(2 * p + 1) * 4194304;
        float* o0 = out + (size_t)(2 * p) * 4194304;
        float* o1 = out + (size_t)(2 * p + 1) * 4194304;
        qkv_gemm<<<dim3(768), 256, 0, stream>>>(x0, Wt, Qb, Kb, V0);
        if (big) qk_gemm<true><<<dim3(1024), 256, 0, stream>>>(Qb, Kb, P0, plg);
        else     qk_gemm<false><<<dim3(1024), 256, 0, stream>>>(Qb, Kb, P0, nullptr);
        qkv_gemm<<<dim3(768), 256, 0, stream>>>(x1, Wt, Qb, Kb, V1);
        if (big) qk_gemm<true><<<dim3(1024), 256, 0, stream>>>(Qb, Kb, P1, plg + 4096 * 64);
        else     qk_gemm<false><<<dim3(1024), 256, 0, stream>>>(Qb, Kb, P1, nullptr);
        if (big) {
            pv_pair<0><<<dim3(512), 256, 0, stream>>>(P0, P1, V0, V1, plg, o0, o1);
        } else {
            rowsum_pair<<<dim3(2048), 256, 0, stream>>>(P0, P1, rlb);
            pv_pair<1><<<dim3(512), 256, 0, stream>>>(P0, P1, V0, V1, rlb, o0, o1);
        }
    }
}